// Round 10
// baseline (272.785 us; speedup 1.0000x reference)
//
#include <hip/hip_runtime.h>
#include <math.h>

// Greedy farthest-point selection via precomputed Gram triangle.
// NEW pipeline (ws >= 191.2 MB):
//   kprep : video f32 -> hi/lo f16 split planes in FRAGMENT-MAJOR layout
//           ([b][plane][rg16][kc][lane][8]) + row inv-norms. One pass.
//   kgram2: LDS-free, barrier-free MFMA Gram: each lane loads its fragment
//           with a single coalesced 16B global load (L1/L2-resident),
//           12 MFMA per chunk-wave, 3-product f16-split (validated R5-R9).
//   kfused: greedy argmin on G (wave 0) + gather (all waves).
// Fallback (ws >= 23.1 MB): R9-proven LDS kgram + kfused.
// Fallback (tiny ws): R5-proven 3-kernel split path, G in out_v region.

constexpr int BB = 128, NN = 300, DV = 1024, DA = 128, KK = 64;
constexpr int TRI = NN * (NN + 1) / 2;        // 45150
constexpr int TB = 64;
constexpr int NTILES = 15;
constexpr int KC = 32;
constexpr int NCH = DV / KC;                  // 32 chunks
constexpr int LDH = 36;                       // R9 fallback LDS stride
constexpr int NRG = 20;                       // row-groups of 16 (320 rows padded)

// ws layout
constexpr size_t FRAG_U     = (size_t)NRG * NCH * 64;        // f16x8 units/plane = 40960
constexpr size_t FRAG_BYTES = FRAG_U * 16 * 2 * BB;          // 167,772,160
constexpr size_t INV_OFF    = FRAG_BYTES;
constexpr size_t INV_BYTES  = (size_t)BB * NN * 8;           // 307,200
constexpr size_t G_OFF      = INV_OFF + INV_BYTES;           // 168,079,360
constexpr size_t WS_NEED    = G_OFF + (size_t)BB * TRI * 4;  // 191,196,160

__device__ __constant__ int c_ib[NTILES] = {0,0,0,0,0, 1,1,1,1, 2,2,2, 3,3, 4};
__device__ __constant__ int c_jb[NTILES] = {0,1,2,3,4, 1,2,3,4, 2,3,4, 3,4, 4};

typedef _Float16 f16x8 __attribute__((ext_vector_type(8)));
typedef float    f32x4 __attribute__((ext_vector_type(4)));

union H4 { _Float16 h[4]; uint2 u; };
union H8 { _Float16 h[8]; f16x8 v; };
union F8 { uint2 u2[2]; f16x8 v; };

__device__ __forceinline__ int tri_base(int i) { return i * NN - (i * (i - 1)) / 2; }

// ---------------- 0. kprep: split + fragment-major layout + norms ----------
// Block = (rg, b), 256 threads. Lane (g,c16) of wave w handles row rg*16+c16,
// k-slots {kc*32 + 4g..4g+3, +16} for kc = w, w+4, ... (the fragment k-map).
__global__ __launch_bounds__(256) void kprep(const float* __restrict__ video,
                                             _Float16* __restrict__ F,
                                             double* __restrict__ invn) {
    const int rg = blockIdx.x, b = blockIdx.y;
    const int tid = threadIdx.x, w = tid >> 6, lane = tid & 63;
    const int g = lane >> 4, c16 = lane & 15;
    const int row = rg * 16 + c16;
    const bool rv = row < NN;
    const float* vr = video + (size_t)b * NN * DV + (size_t)(rv ? row : 0) * DV;
    const float4 z4 = make_float4(0.f, 0.f, 0.f, 0.f);

    f16x8* Fv = (f16x8*)F;
    const size_t baseHi = ((size_t)(b * 2 + 0) * NRG + rg) * (NCH * 64) + lane;
    const size_t baseLo = ((size_t)(b * 2 + 1) * NRG + rg) * (NCH * 64) + lane;

    float ps = 0.f;
    for (int kc = w; kc < NCH; kc += 4) {
        const int k0 = kc * KC;
        float4 a = rv ? *(const float4*)(vr + k0 + 4 * g) : z4;
        float4 c = rv ? *(const float4*)(vr + k0 + 16 + 4 * g) : z4;
        ps = fmaf(a.x, a.x, fmaf(a.y, a.y, fmaf(a.z, a.z, fmaf(a.w, a.w, ps))));
        ps = fmaf(c.x, c.x, fmaf(c.y, c.y, fmaf(c.z, c.z, fmaf(c.w, c.w, ps))));
        float s[8] = {a.x, a.y, a.z, a.w, c.x, c.y, c.z, c.w};
        H8 hi, lo;
        #pragma unroll
        for (int e = 0; e < 8; ++e) {
            _Float16 h = (_Float16)s[e];
            hi.h[e] = h;
            lo.h[e] = (_Float16)(s[e] - (float)h);
        }
        Fv[baseHi + kc * 64] = hi.v;
        Fv[baseLo + kc * 64] = lo.v;
    }

    // norm: sum over g (lane bits 4,5), then over waves via LDS, f64 master
    ps += __shfl_xor(ps, 16, 64);
    ps += __shfl_xor(ps, 32, 64);
    __shared__ float sr[4][16];
    if (lane < 16) sr[w][c16] = ps;
    __syncthreads();
    if (tid < 16) {
        const int rr = rg * 16 + tid;
        if (rr < NN) {
            double sum = (double)sr[0][tid] + (double)sr[1][tid]
                       + (double)sr[2][tid] + (double)sr[3][tid];
            invn[b * NN + rr] = 1.0 / (sqrt(sum) + 1e-5);
        }
    }
}

// ---------------- 1a. kgram2: LDS-free fragment-direct MFMA ----------------
__global__ __launch_bounds__(256) void kgram2(const _Float16* __restrict__ F,
                                              const double* __restrict__ invn,
                                              float* __restrict__ G) {
    const int bid  = blockIdx.x;
    const int swz  = (bid & 7) * 240 + (bid >> 3);      // bijective: 1920=8*240
    const int batch = swz / 15;
    const int tile  = swz - batch * 15;
    const int i0 = c_ib[tile] * TB, j0 = c_jb[tile] * TB;
    const int tid = threadIdx.x, lane = tid & 63, w = tid >> 6;
    const int wr = w >> 1, wc = w & 1;
    const int g = lane >> 4, c16 = lane & 15;

    const f16x8* Fv = (const f16x8*)F;
    const f16x8 *pAh[2], *pAl[2], *pBh[2], *pBl[2];
    #pragma unroll
    for (int fr = 0; fr < 2; ++fr) {
        const int rgA = (i0 >> 4) + 2 * wr + fr;
        const int rgB = (j0 >> 4) + 2 * wc + fr;
        pAh[fr] = Fv + ((size_t)(batch * 2 + 0) * NRG + rgA) * (NCH * 64) + lane;
        pAl[fr] = Fv + ((size_t)(batch * 2 + 1) * NRG + rgA) * (NCH * 64) + lane;
        pBh[fr] = Fv + ((size_t)(batch * 2 + 0) * NRG + rgB) * (NCH * 64) + lane;
        pBl[fr] = Fv + ((size_t)(batch * 2 + 1) * NRG + rgB) * (NCH * 64) + lane;
    }

    f32x4 acc[2][2];
    #pragma unroll
    for (int fr = 0; fr < 2; ++fr)
        #pragma unroll
        for (int fc = 0; fc < 2; ++fc) acc[fr][fc] = (f32x4){0.f, 0.f, 0.f, 0.f};

    #pragma unroll 2
    for (int kc = 0; kc < NCH; ++kc) {
        const int o = kc * 64;
        f16x8 Ah[2], Al[2], Bh[2], Bl[2];
        #pragma unroll
        for (int fr = 0; fr < 2; ++fr) {
            Ah[fr] = pAh[fr][o]; Al[fr] = pAl[fr][o];
            Bh[fr] = pBh[fr][o]; Bl[fr] = pBl[fr][o];
        }
        #pragma unroll
        for (int fr = 0; fr < 2; ++fr)
            #pragma unroll
            for (int fc = 0; fc < 2; ++fc) {
                acc[fr][fc] = __builtin_amdgcn_mfma_f32_16x16x32_f16(Ah[fr], Bh[fc], acc[fr][fc], 0, 0, 0);
                acc[fr][fc] = __builtin_amdgcn_mfma_f32_16x16x32_f16(Ah[fr], Bl[fc], acc[fr][fc], 0, 0, 0);
                acc[fr][fc] = __builtin_amdgcn_mfma_f32_16x16x32_f16(Al[fr], Bh[fc], acc[fr][fc], 0, 0, 0);
            }
    }

    const double* invb = invn + batch * NN;
    float* Gb = G + (size_t)batch * TRI;
    #pragma unroll
    for (int fr = 0; fr < 2; ++fr)
        #pragma unroll
        for (int fc = 0; fc < 2; ++fc)
            #pragma unroll
            for (int reg = 0; reg < 4; ++reg) {
                const int il = 32 * wr + 16 * fr + 4 * g + reg;   // D row (m89)
                const int jl = 32 * wc + 16 * fc + c16;           // D col (m89)
                const int i = i0 + il, j = j0 + jl;
                if (i <= j && j < NN)
                    Gb[tri_base(i) + (j - i)] =
                        (float)(fabs((double)acc[fr][fc][reg]) * invb[i] * invb[j]);
            }
}

// ---------------- 1b. R9 fallback: LDS double-buffered kgram ----------------
__global__ __launch_bounds__(256) void kgram_lds(const float* __restrict__ video,
                                                 float* __restrict__ G) {
    const int bid  = blockIdx.x;
    const int swz  = (bid & 7) * 240 + (bid >> 3);
    const int batch = swz / 15;
    const int tile  = swz - batch * 15;
    const int i0 = c_ib[tile] * TB, j0 = c_jb[tile] * TB;
    const bool diag = (i0 == j0);
    const int tid = threadIdx.x;

    __shared__ _Float16 sH[2][4][TB][LDH];
    __shared__ float    s_part[256];
    __shared__ double   s_inv[2][TB];

    const float* vb = video + (size_t)batch * NN * DV;

    const int slab  = tid >> 7;
    const int lrow  = (tid >> 1) & 63;
    const int khalf = tid & 1;
    const int grow  = (slab ? j0 : i0) + lrow;
    const bool rok  = grow < NN;
    const bool stage_on = !(diag && slab == 1);
    const float4* srcb4 = (const float4*)(vb + (size_t)(rok ? grow : 0) * DV);
    const int qbase = khalf * 4;

    const int lane = tid & 63, w = tid >> 6;
    const int wr = w >> 1, wc = w & 1;
    const int g = lane >> 4, c16 = lane & 15;
    const int bplane = diag ? 0 : 2;

    f32x4 acc[2][2];
    #pragma unroll
    for (int fr = 0; fr < 2; ++fr)
        #pragma unroll
        for (int fc = 0; fc < 2; ++fc) acc[fr][fc] = (f32x4){0.f, 0.f, 0.f, 0.f};

    float ps = 0.f;
    float4 ld[4];
    const float4 z4 = make_float4(0.f, 0.f, 0.f, 0.f);

    auto stage_write = [&](int bf) {
        #pragma unroll
        for (int q = 0; q < 4; ++q) {
            float4 v = ld[q];
            ps = fmaf(v.x, v.x, fmaf(v.y, v.y, fmaf(v.z, v.z, fmaf(v.w, v.w, ps))));
            H4 hi, lo;
            _Float16 h0 = (_Float16)v.x, h1 = (_Float16)v.y,
                     h2 = (_Float16)v.z, h3 = (_Float16)v.w;
            hi.h[0] = h0; hi.h[1] = h1; hi.h[2] = h2; hi.h[3] = h3;
            lo.h[0] = (_Float16)(v.x - (float)h0);
            lo.h[1] = (_Float16)(v.y - (float)h1);
            lo.h[2] = (_Float16)(v.z - (float)h2);
            lo.h[3] = (_Float16)(v.w - (float)h3);
            const int p = khalf * 16 + 4 * q;
            *(uint2*)&sH[bf][slab * 2 + 0][lrow][p] = hi.u;
            *(uint2*)&sH[bf][slab * 2 + 1][lrow][p] = lo.u;
        }
    };

    if (stage_on) {
        #pragma unroll
        for (int q = 0; q < 4; ++q) ld[q] = rok ? srcb4[qbase + q] : z4;
        stage_write(0);
        #pragma unroll
        for (int q = 0; q < 4; ++q) ld[q] = rok ? srcb4[8 + qbase + q] : z4;
    }
    __syncthreads();

    for (int kc = 0; kc < NCH; ++kc) {
        const int cur = kc & 1, nxt = cur ^ 1;
        if (stage_on && kc < NCH - 1) stage_write(nxt);
        if (stage_on && kc < NCH - 2) {
            #pragma unroll
            for (int q = 0; q < 4; ++q)
                ld[q] = rok ? srcb4[(kc + 2) * 8 + qbase + q] : z4;
        }

        f16x8 Ah[2], Al[2], Bh[2], Bl[2];
        #pragma unroll
        for (int fr = 0; fr < 2; ++fr) {
            const int row = 32 * wr + 16 * fr + c16;
            F8 t;
            t.u2[0] = *(const uint2*)&sH[cur][0][row][4 * g];
            t.u2[1] = *(const uint2*)&sH[cur][0][row][16 + 4 * g];
            Ah[fr] = t.v;
            t.u2[0] = *(const uint2*)&sH[cur][1][row][4 * g];
            t.u2[1] = *(const uint2*)&sH[cur][1][row][16 + 4 * g];
            Al[fr] = t.v;
        }
        #pragma unroll
        for (int fc = 0; fc < 2; ++fc) {
            const int row = 32 * wc + 16 * fc + c16;
            F8 t;
            t.u2[0] = *(const uint2*)&sH[cur][bplane + 0][row][4 * g];
            t.u2[1] = *(const uint2*)&sH[cur][bplane + 0][row][16 + 4 * g];
            Bh[fc] = t.v;
            t.u2[0] = *(const uint2*)&sH[cur][bplane + 1][row][4 * g];
            t.u2[1] = *(const uint2*)&sH[cur][bplane + 1][row][16 + 4 * g];
            Bl[fc] = t.v;
        }
        #pragma unroll
        for (int fr = 0; fr < 2; ++fr)
            #pragma unroll
            for (int fc = 0; fc < 2; ++fc) {
                acc[fr][fc] = __builtin_amdgcn_mfma_f32_16x16x32_f16(Ah[fr], Bh[fc], acc[fr][fc], 0, 0, 0);
                acc[fr][fc] = __builtin_amdgcn_mfma_f32_16x16x32_f16(Ah[fr], Bl[fc], acc[fr][fc], 0, 0, 0);
                acc[fr][fc] = __builtin_amdgcn_mfma_f32_16x16x32_f16(Al[fr], Bh[fc], acc[fr][fc], 0, 0, 0);
            }
        __syncthreads();
    }

    s_part[tid] = ps;
    __syncthreads();
    if (tid < 128) {
        const int st = tid >> 6, r = tid & 63;
        const int src = (st && !diag) ? 128 + 2 * r : 2 * r;
        float ssum = s_part[src] + s_part[src + 1];
        s_inv[st][r] = 1.0 / (sqrt((double)ssum) + 1e-5);
    }
    __syncthreads();

    float* Gb = G + (size_t)batch * TRI;
    #pragma unroll
    for (int fr = 0; fr < 2; ++fr)
        #pragma unroll
        for (int fc = 0; fc < 2; ++fc)
            #pragma unroll
            for (int reg = 0; reg < 4; ++reg) {
                const int il = 32 * wr + 16 * fr + 4 * g + reg;
                const int jl = 32 * wc + 16 * fc + c16;
                const int i = i0 + il, j = j0 + jl;
                if (i <= j && j < NN)
                    Gb[tri_base(i) + (j - i)] =
                        (float)(fabs((double)acc[fr][fc][reg]) * s_inv[0][il] * s_inv[1][jl]);
            }
}

// ---- device helper: greedy selection for one batch, one wave ----
__device__ __forceinline__ void select_wave(const float* __restrict__ Gb,
                                            int lane, int* s_sorted) {
    float best[5];
    int myidx = 0;

    #pragma unroll
    for (int q = 0; q < 5; ++q) {
        int r = lane + 64 * q;
        best[q] = (r < NN) ? Gb[r] : 3.4e38f;
    }

    int last;
    {
        float v = INFINITY; int ri = 1 << 30;
        #pragma unroll
        for (int q = 0; q < 5; ++q)
            if (best[q] < v) { v = best[q]; ri = lane + 64 * q; }
        #pragma unroll
        for (int off = 32; off >= 1; off >>= 1) {
            float ov = __shfl_xor(v, off, 64); int oi = __shfl_xor(ri, off, 64);
            if (ov < v || (ov == v && oi < ri)) { v = ov; ri = oi; }
        }
        last = ri;
    }
    if (lane == 1) myidx = last;

    for (int t = 2; t < KK; ++t) {
        #pragma unroll
        for (int q = 0; q < 5; ++q) {
            int r = lane + 64 * q;
            if (r < NN) {
                int i = min(last, r), j = max(last, r);
                best[q] = fmaxf(best[q], Gb[tri_base(i) + (j - i)]);
            }
        }
        float v = INFINITY; int ri = 1 << 30;
        #pragma unroll
        for (int q = 0; q < 5; ++q)
            if (best[q] < v) { v = best[q]; ri = lane + 64 * q; }
        #pragma unroll
        for (int off = 32; off >= 1; off >>= 1) {
            float ov = __shfl_xor(v, off, 64); int oi = __shfl_xor(ri, off, 64);
            if (ov < v || (ov == v && oi < ri)) { v = ov; ri = oi; }
        }
        last = ri;
        if (lane == t) myidx = last;
    }

    int rank = 0;
    for (int j = 0; j < KK; ++j) {
        int oj = __shfl(myidx, j, 64);
        rank += (oj < myidx) || (oj == myidx && j < lane);
    }
    s_sorted[rank] = myidx;
}

// ---------------- 2a. fused selection + gather (G in d_ws) ----------------
__global__ __launch_bounds__(256) void kfused(const float* __restrict__ G,
                                              const float* __restrict__ video,
                                              const float* __restrict__ audio,
                                              float* __restrict__ out_v,
                                              float* __restrict__ out_a) {
    const int b = blockIdx.x, tid = threadIdx.x;
    __shared__ int s_sorted[KK];

    if (tid < 64)
        select_wave(G + (size_t)b * TRI, tid, s_sorted);
    __syncthreads();

    const float4* vb4 = (const float4*)(video + (size_t)b * NN * DV);
    float4* ov4 = (float4*)(out_v + (size_t)b * KK * DV);
    #pragma unroll 4
    for (int t = tid; t < KK * DV / 4; t += 256) {
        int k = t >> 8, c = t & 255;
        ov4[t] = vb4[s_sorted[k] * (DV / 4) + c];
    }
    const float4* ab4 = (const float4*)(audio + (size_t)b * NN * DA);
    float4* oa4 = (float4*)(out_a + (size_t)b * KK * DA);
    for (int t = tid; t < KK * DA / 4; t += 256) {
        int k = t >> 5, c = t & 31;
        oa4[t] = ab4[s_sorted[k] * (DA / 4) + c];
    }
}

// ---------------- 2b/2c. split fallback (G in out_v region) ----------------
__global__ __launch_bounds__(64) void kselect(const float* __restrict__ G,
                                              float* __restrict__ out_a) {
    __shared__ int s_sorted[KK];
    select_wave(G + (size_t)blockIdx.x * TRI, threadIdx.x, s_sorted);
    __syncthreads();
    ((int*)(out_a + (size_t)blockIdx.x * KK * DA))[threadIdx.x] = s_sorted[threadIdx.x];
}

__global__ __launch_bounds__(256) void kgather(const float* __restrict__ video,
                                               const float* __restrict__ audio,
                                               float* __restrict__ out_v,
                                               float* __restrict__ out_a) {
    int b = blockIdx.x, tid = threadIdx.x;
    __shared__ int s_idx[KK];
    const int* idxp = (const int*)(out_a + (size_t)b * KK * DA);
    if (tid < KK) s_idx[tid] = idxp[tid];
    __syncthreads();

    const float4* vb4 = (const float4*)(video + (size_t)b * NN * DV);
    float4* ov4 = (float4*)(out_v + (size_t)b * KK * DV);
    #pragma unroll 4
    for (int t = tid; t < KK * DV / 4; t += 256) {
        int k = t >> 8, c = t & 255;
        ov4[t] = vb4[s_idx[k] * (DV / 4) + c];
    }
    const float4* ab4 = (const float4*)(audio + (size_t)b * NN * DA);
    float4* oa4 = (float4*)(out_a + (size_t)b * KK * DA);
    for (int t = tid; t < KK * DA / 4; t += 256) {
        int k = t >> 5, c = t & 31;
        oa4[t] = ab4[s_idx[k] * (DA / 4) + c];
    }
}

extern "C" void kernel_launch(void* const* d_in, const int* in_sizes, int n_in,
                              void* d_out, int out_size, void* d_ws, size_t ws_size,
                              hipStream_t stream) {
    const float* video = (const float*)d_in[0];
    const float* audio = (const float*)d_in[1];
    float* out   = (float*)d_out;
    float* out_v = out;
    float* out_a = out + (size_t)BB * KK * DV;

    const size_t g_bytes = (size_t)BB * TRI * sizeof(float);   // 23.1 MB

    if (ws_size >= WS_NEED) {
        _Float16* F  = (_Float16*)d_ws;
        double* invn = (double*)((char*)d_ws + INV_OFF);
        float* G     = (float*)((char*)d_ws + G_OFF);
        kprep <<<dim3(NRG, BB), 256, 0, stream>>>(video, F, invn);
        kgram2<<<NTILES * BB, 256, 0, stream>>>(F, invn, G);
        kfused<<<BB, 256, 0, stream>>>(G, video, audio, out_v, out_a);
    } else if (ws_size >= g_bytes) {
        float* G = (float*)d_ws;
        kgram_lds<<<NTILES * BB, 256, 0, stream>>>(video, G);
        kfused   <<<BB, 256, 0, stream>>>(G, video, audio, out_v, out_a);
    } else {
        float* G = out;
        kgram_lds<<<NTILES * BB, 256, 0, stream>>>(video, G);
        kselect  <<<BB, 64, 0, stream>>>(G, out_a);
        kgather  <<<BB, 256, 0, stream>>>(video, audio, out_v, out_a);
    }
}

// Round 11
// 214.559 us; speedup vs baseline: 1.2714x; 1.2714x over previous
//
#include <hip/hip_runtime.h>
#include <math.h>

// Greedy farthest-point selection via precomputed Gram matrix.
// kgram3 : 128x128-tile MFMA Gram (f16 2-way split, 3 products, f32 accum,
//          double-buffered LDS, one barrier/chunk) writing SQUARE G (stride
//          304, both triangles) -> contiguous selection reads.
// kfused : greedy argmin on square G (wave 0) + gather (all waves).
// Fallbacks: tri-G R9 path (ws >= 23.1 MB), then 3-kernel split path.

constexpr int BB = 128, NN = 300, DV = 1024, DA = 128, KK = 64;
constexpr int TRI = NN * (NN + 1) / 2;        // 45150
constexpr int KC = 32;
constexpr int NCH = DV / KC;                  // 32 chunks
constexpr int LDH = 36;                       // f16 row stride: 72 B

// square-G geometry
constexpr int GS = 304;                       // padded row stride (floats)
constexpr int GBATCH = NN * GS;               // 91200 floats/batch
constexpr size_t SQ_NEED = (size_t)BB * GBATCH * 4;   // 46.7 MB

// 128-tiles of the 300x300 triangle: 3 row-blocks -> 6 tiles
constexpr int NT2 = 6;
__device__ __constant__ int t2_ib[NT2] = {0,0,0,1,1,2};
__device__ __constant__ int t2_jb[NT2] = {0,1,2,1,2,2};

// 64-tiles (fallback path)
constexpr int NTILES = 15;
constexpr int TB = 64;
__device__ __constant__ int c_ib[NTILES] = {0,0,0,0,0, 1,1,1,1, 2,2,2, 3,3, 4};
__device__ __constant__ int c_jb[NTILES] = {0,1,2,3,4, 1,2,3,4, 2,3,4, 3,4, 4};

typedef _Float16 f16x8 __attribute__((ext_vector_type(8)));
typedef float    f32x4 __attribute__((ext_vector_type(4)));

union H4 { _Float16 h[4]; uint2 u; };
union F8 { uint2 u2[2]; f16x8 v; };

__device__ __forceinline__ int tri_base(int i) { return i * NN - (i * (i - 1)) / 2; }

// ---------------- 1a. kgram3: 128-tile, square-G output ----------------
// Grid 768 = 6 tiles x 128 batches, XCD-swizzled (768 = 8*96; 16 batches/XCD).
// 512 threads = 8 waves; wave w -> 64x32 quadrant (wr2=w>>2, wc2=w&3) as
// 4x2 16x16x32 fragments. Staging: thread -> (slab, row128, khalf).
// Numerics identical to R9: RNE hi + RNE lo residual, hi*hi + hi*lo + lo*hi
// per chunk in that order, same fragment k-map for A and B.
__global__ __launch_bounds__(512, 4) void kgram3(const float* __restrict__ video,
                                                 float* __restrict__ G) {
    const int bid  = blockIdx.x;
    const int swz  = (bid & 7) * 96 + (bid >> 3);       // bijective: 768=8*96
    const int batch = swz / NT2;
    const int tile  = swz - batch * NT2;
    const int i0 = t2_ib[tile] * 128, j0 = t2_jb[tile] * 128;
    const bool diag = (i0 == j0);
    const int tid = threadIdx.x;

    __shared__ _Float16 sH[2][4][128][LDH];   // [buf][A-hi,A-lo,B-hi,B-lo] 72 KB
    __shared__ float    s_part[512];
    __shared__ double   s_inv[2][128];

    const float* vb = video + (size_t)batch * NN * DV;

    // staging role
    const int slab  = tid >> 8;               // 0=A(i-rows), 1=B(j-rows)
    const int st    = tid & 255;
    const int lrow  = st >> 1;                // 0..127
    const int khalf = st & 1;
    const int grow  = (slab ? j0 : i0) + lrow;
    const bool rok  = grow < NN;
    const bool stage_on = !(diag && slab == 1);
    const float4* srcb4 = (const float4*)(vb + (size_t)(rok ? grow : 0) * DV);
    const int qbase = khalf * 4;

    // compute role
    const int lane = tid & 63, w = tid >> 6;
    const int wr2 = w >> 2, wc2 = w & 3;
    const int g = lane >> 4, c16 = lane & 15;
    const int bplane = diag ? 0 : 2;

    f32x4 acc[4][2];
    #pragma unroll
    for (int fr = 0; fr < 4; ++fr)
        #pragma unroll
        for (int fc = 0; fc < 2; ++fc) acc[fr][fc] = (f32x4){0.f, 0.f, 0.f, 0.f};

    float ps = 0.f;
    float4 ld[4];
    const float4 z4 = make_float4(0.f, 0.f, 0.f, 0.f);

    auto stage_write = [&](int bf) {
        #pragma unroll
        for (int q = 0; q < 4; ++q) {
            float4 v = ld[q];
            ps = fmaf(v.x, v.x, fmaf(v.y, v.y, fmaf(v.z, v.z, fmaf(v.w, v.w, ps))));
            H4 hi, lo;
            _Float16 h0 = (_Float16)v.x, h1 = (_Float16)v.y,
                     h2 = (_Float16)v.z, h3 = (_Float16)v.w;
            hi.h[0] = h0; hi.h[1] = h1; hi.h[2] = h2; hi.h[3] = h3;
            lo.h[0] = (_Float16)(v.x - (float)h0);
            lo.h[1] = (_Float16)(v.y - (float)h1);
            lo.h[2] = (_Float16)(v.z - (float)h2);
            lo.h[3] = (_Float16)(v.w - (float)h3);
            const int p = khalf * 16 + 4 * q;
            *(uint2*)&sH[bf][slab * 2 + 0][lrow][p] = hi.u;
            *(uint2*)&sH[bf][slab * 2 + 1][lrow][p] = lo.u;
        }
    };

    if (stage_on) {
        #pragma unroll
        for (int q = 0; q < 4; ++q) ld[q] = rok ? srcb4[qbase + q] : z4;
        stage_write(0);
        #pragma unroll
        for (int q = 0; q < 4; ++q) ld[q] = rok ? srcb4[8 + qbase + q] : z4;
    }
    __syncthreads();

    for (int kc = 0; kc < NCH; ++kc) {
        const int cur = kc & 1, nxt = cur ^ 1;
        if (stage_on && kc < NCH - 1) stage_write(nxt);
        if (stage_on && kc < NCH - 2) {
            #pragma unroll
            for (int q = 0; q < 4; ++q)
                ld[q] = rok ? srcb4[(kc + 2) * 8 + qbase + q] : z4;
        }

        f16x8 Ah[4], Al[4], Bh[2], Bl[2];
        #pragma unroll
        for (int fr = 0; fr < 4; ++fr) {
            const int row = 64 * wr2 + 16 * fr + c16;
            F8 t;
            t.u2[0] = *(const uint2*)&sH[cur][0][row][4 * g];
            t.u2[1] = *(const uint2*)&sH[cur][0][row][16 + 4 * g];
            Ah[fr] = t.v;
            t.u2[0] = *(const uint2*)&sH[cur][1][row][4 * g];
            t.u2[1] = *(const uint2*)&sH[cur][1][row][16 + 4 * g];
            Al[fr] = t.v;
        }
        #pragma unroll
        for (int fc = 0; fc < 2; ++fc) {
            const int row = 32 * wc2 + 16 * fc + c16;
            F8 t;
            t.u2[0] = *(const uint2*)&sH[cur][bplane + 0][row][4 * g];
            t.u2[1] = *(const uint2*)&sH[cur][bplane + 0][row][16 + 4 * g];
            Bh[fc] = t.v;
            t.u2[0] = *(const uint2*)&sH[cur][bplane + 1][row][4 * g];
            t.u2[1] = *(const uint2*)&sH[cur][bplane + 1][row][16 + 4 * g];
            Bl[fc] = t.v;
        }
        #pragma unroll
        for (int fr = 0; fr < 4; ++fr)
            #pragma unroll
            for (int fc = 0; fc < 2; ++fc) {
                acc[fr][fc] = __builtin_amdgcn_mfma_f32_16x16x32_f16(Ah[fr], Bh[fc], acc[fr][fc], 0, 0, 0);
                acc[fr][fc] = __builtin_amdgcn_mfma_f32_16x16x32_f16(Ah[fr], Bl[fc], acc[fr][fc], 0, 0, 0);
                acc[fr][fc] = __builtin_amdgcn_mfma_f32_16x16x32_f16(Al[fr], Bh[fc], acc[fr][fc], 0, 0, 0);
            }
        __syncthreads();
    }

    // ---- norms ----
    s_part[tid] = ps;
    __syncthreads();
    if (tid < 256) {
        const int sl = tid >> 7, r = tid & 127;
        const int src = (sl && !diag) ? 256 + 2 * r : 2 * r;
        float ssum = s_part[src] + s_part[src + 1];
        s_inv[sl][r] = 1.0 / (sqrt((double)ssum) + 1e-5);
    }
    __syncthreads();

    float* Gb = G + (size_t)batch * GBATCH;
    #pragma unroll
    for (int fr = 0; fr < 4; ++fr)
        #pragma unroll
        for (int fc = 0; fc < 2; ++fc)
            #pragma unroll
            for (int reg = 0; reg < 4; ++reg) {
                const int il = 64 * wr2 + 16 * fr + 4 * g + reg;  // D row (m89)
                const int jl = 32 * wc2 + 16 * fc + c16;          // D col (m89)
                const int i = i0 + il, j = j0 + jl;
                if (i <= j && j < NN) {
                    float val = (float)(fabs((double)acc[fr][fc][reg]) *
                                        s_inv[0][il] * s_inv[1][jl]);
                    Gb[i * GS + j] = val;
                    Gb[j * GS + i] = val;
                }
            }
}

// ---------------- 1b. fallback: R9 64-tile tri-G kgram ----------------
__global__ __launch_bounds__(256) void kgram_lds(const float* __restrict__ video,
                                                 float* __restrict__ G) {
    const int bid  = blockIdx.x;
    const int swz  = (bid & 7) * 240 + (bid >> 3);
    const int batch = swz / 15;
    const int tile  = swz - batch * 15;
    const int i0 = c_ib[tile] * TB, j0 = c_jb[tile] * TB;
    const bool diag = (i0 == j0);
    const int tid = threadIdx.x;

    __shared__ _Float16 sH[2][4][TB][LDH];
    __shared__ float    s_part[256];
    __shared__ double   s_inv[2][TB];

    const float* vb = video + (size_t)batch * NN * DV;

    const int slab  = tid >> 7;
    const int lrow  = (tid >> 1) & 63;
    const int khalf = tid & 1;
    const int grow  = (slab ? j0 : i0) + lrow;
    const bool rok  = grow < NN;
    const bool stage_on = !(diag && slab == 1);
    const float4* srcb4 = (const float4*)(vb + (size_t)(rok ? grow : 0) * DV);
    const int qbase = khalf * 4;

    const int lane = tid & 63, w = tid >> 6;
    const int wr = w >> 1, wc = w & 1;
    const int g = lane >> 4, c16 = lane & 15;
    const int bplane = diag ? 0 : 2;

    f32x4 acc[2][2];
    #pragma unroll
    for (int fr = 0; fr < 2; ++fr)
        #pragma unroll
        for (int fc = 0; fc < 2; ++fc) acc[fr][fc] = (f32x4){0.f, 0.f, 0.f, 0.f};

    float ps = 0.f;
    float4 ld[4];
    const float4 z4 = make_float4(0.f, 0.f, 0.f, 0.f);

    auto stage_write = [&](int bf) {
        #pragma unroll
        for (int q = 0; q < 4; ++q) {
            float4 v = ld[q];
            ps = fmaf(v.x, v.x, fmaf(v.y, v.y, fmaf(v.z, v.z, fmaf(v.w, v.w, ps))));
            H4 hi, lo;
            _Float16 h0 = (_Float16)v.x, h1 = (_Float16)v.y,
                     h2 = (_Float16)v.z, h3 = (_Float16)v.w;
            hi.h[0] = h0; hi.h[1] = h1; hi.h[2] = h2; hi.h[3] = h3;
            lo.h[0] = (_Float16)(v.x - (float)h0);
            lo.h[1] = (_Float16)(v.y - (float)h1);
            lo.h[2] = (_Float16)(v.z - (float)h2);
            lo.h[3] = (_Float16)(v.w - (float)h3);
            const int p = khalf * 16 + 4 * q;
            *(uint2*)&sH[bf][slab * 2 + 0][lrow][p] = hi.u;
            *(uint2*)&sH[bf][slab * 2 + 1][lrow][p] = lo.u;
        }
    };

    if (stage_on) {
        #pragma unroll
        for (int q = 0; q < 4; ++q) ld[q] = rok ? srcb4[qbase + q] : z4;
        stage_write(0);
        #pragma unroll
        for (int q = 0; q < 4; ++q) ld[q] = rok ? srcb4[8 + qbase + q] : z4;
    }
    __syncthreads();

    for (int kc = 0; kc < NCH; ++kc) {
        const int cur = kc & 1, nxt = cur ^ 1;
        if (stage_on && kc < NCH - 1) stage_write(nxt);
        if (stage_on && kc < NCH - 2) {
            #pragma unroll
            for (int q = 0; q < 4; ++q)
                ld[q] = rok ? srcb4[(kc + 2) * 8 + qbase + q] : z4;
        }

        f16x8 Ah[2], Al[2], Bh[2], Bl[2];
        #pragma unroll
        for (int fr = 0; fr < 2; ++fr) {
            const int row = 32 * wr + 16 * fr + c16;
            F8 t;
            t.u2[0] = *(const uint2*)&sH[cur][0][row][4 * g];
            t.u2[1] = *(const uint2*)&sH[cur][0][row][16 + 4 * g];
            Ah[fr] = t.v;
            t.u2[0] = *(const uint2*)&sH[cur][1][row][4 * g];
            t.u2[1] = *(const uint2*)&sH[cur][1][row][16 + 4 * g];
            Al[fr] = t.v;
        }
        #pragma unroll
        for (int fc = 0; fc < 2; ++fc) {
            const int row = 32 * wc + 16 * fc + c16;
            F8 t;
            t.u2[0] = *(const uint2*)&sH[cur][bplane + 0][row][4 * g];
            t.u2[1] = *(const uint2*)&sH[cur][bplane + 0][row][16 + 4 * g];
            Bh[fc] = t.v;
            t.u2[0] = *(const uint2*)&sH[cur][bplane + 1][row][4 * g];
            t.u2[1] = *(const uint2*)&sH[cur][bplane + 1][row][16 + 4 * g];
            Bl[fc] = t.v;
        }
        #pragma unroll
        for (int fr = 0; fr < 2; ++fr)
            #pragma unroll
            for (int fc = 0; fc < 2; ++fc) {
                acc[fr][fc] = __builtin_amdgcn_mfma_f32_16x16x32_f16(Ah[fr], Bh[fc], acc[fr][fc], 0, 0, 0);
                acc[fr][fc] = __builtin_amdgcn_mfma_f32_16x16x32_f16(Ah[fr], Bl[fc], acc[fr][fc], 0, 0, 0);
                acc[fr][fc] = __builtin_amdgcn_mfma_f32_16x16x32_f16(Al[fr], Bh[fc], acc[fr][fc], 0, 0, 0);
            }
        __syncthreads();
    }

    s_part[tid] = ps;
    __syncthreads();
    if (tid < 128) {
        const int sl = tid >> 6, r = tid & 63;
        const int src = (sl && !diag) ? 128 + 2 * r : 2 * r;
        float ssum = s_part[src] + s_part[src + 1];
        s_inv[sl][r] = 1.0 / (sqrt((double)ssum) + 1e-5);
    }
    __syncthreads();

    float* Gb = G + (size_t)batch * TRI;
    #pragma unroll
    for (int fr = 0; fr < 2; ++fr)
        #pragma unroll
        for (int fc = 0; fc < 2; ++fc)
            #pragma unroll
            for (int reg = 0; reg < 4; ++reg) {
                const int il = 32 * wr + 16 * fr + 4 * g + reg;
                const int jl = 32 * wc + 16 * fc + c16;
                const int i = i0 + il, j = j0 + jl;
                if (i <= j && j < NN)
                    Gb[tri_base(i) + (j - i)] =
                        (float)(fabs((double)acc[fr][fc][reg]) * s_inv[0][il] * s_inv[1][jl]);
            }
}

// ---- selection helpers (identical decision sequence; addressing differs) ----
__device__ __forceinline__ void select_wave_sq(const float* __restrict__ Gb,
                                               int lane, int* s_sorted) {
    float best[5];
    int myidx = 0;

    #pragma unroll
    for (int q = 0; q < 5; ++q) {
        int r = lane + 64 * q;
        best[q] = (r < NN) ? Gb[r] : 3.4e38f;       // row 0
    }

    int last;
    {
        float v = INFINITY; int ri = 1 << 30;
        #pragma unroll
        for (int q = 0; q < 5; ++q)
            if (best[q] < v) { v = best[q]; ri = lane + 64 * q; }
        #pragma unroll
        for (int off = 32; off >= 1; off >>= 1) {
            float ov = __shfl_xor(v, off, 64); int oi = __shfl_xor(ri, off, 64);
            if (ov < v || (ov == v && oi < ri)) { v = ov; ri = oi; }
        }
        last = ri;
    }
    if (lane == 1) myidx = last;

    for (int t = 2; t < KK; ++t) {
        const float* row = Gb + last * GS;
        #pragma unroll
        for (int q = 0; q < 5; ++q) {
            int r = lane + 64 * q;
            if (r < NN) best[q] = fmaxf(best[q], row[r]);
        }
        float v = INFINITY; int ri = 1 << 30;
        #pragma unroll
        for (int q = 0; q < 5; ++q)
            if (best[q] < v) { v = best[q]; ri = lane + 64 * q; }
        #pragma unroll
        for (int off = 32; off >= 1; off >>= 1) {
            float ov = __shfl_xor(v, off, 64); int oi = __shfl_xor(ri, off, 64);
            if (ov < v || (ov == v && oi < ri)) { v = ov; ri = oi; }
        }
        last = ri;
        if (lane == t) myidx = last;
    }

    int rank = 0;
    for (int j = 0; j < KK; ++j) {
        int oj = __shfl(myidx, j, 64);
        rank += (oj < myidx) || (oj == myidx && j < lane);
    }
    s_sorted[rank] = myidx;
}

__device__ __forceinline__ void select_wave_tri(const float* __restrict__ Gb,
                                                int lane, int* s_sorted) {
    float best[5];
    int myidx = 0;

    #pragma unroll
    for (int q = 0; q < 5; ++q) {
        int r = lane + 64 * q;
        best[q] = (r < NN) ? Gb[r] : 3.4e38f;
    }

    int last;
    {
        float v = INFINITY; int ri = 1 << 30;
        #pragma unroll
        for (int q = 0; q < 5; ++q)
            if (best[q] < v) { v = best[q]; ri = lane + 64 * q; }
        #pragma unroll
        for (int off = 32; off >= 1; off >>= 1) {
            float ov = __shfl_xor(v, off, 64); int oi = __shfl_xor(ri, off, 64);
            if (ov < v || (ov == v && oi < ri)) { v = ov; ri = oi; }
        }
        last = ri;
    }
    if (lane == 1) myidx = last;

    for (int t = 2; t < KK; ++t) {
        #pragma unroll
        for (int q = 0; q < 5; ++q) {
            int r = lane + 64 * q;
            if (r < NN) {
                int i = min(last, r), j = max(last, r);
                best[q] = fmaxf(best[q], Gb[tri_base(i) + (j - i)]);
            }
        }
        float v = INFINITY; int ri = 1 << 30;
        #pragma unroll
        for (int q = 0; q < 5; ++q)
            if (best[q] < v) { v = best[q]; ri = lane + 64 * q; }
        #pragma unroll
        for (int off = 32; off >= 1; off >>= 1) {
            float ov = __shfl_xor(v, off, 64); int oi = __shfl_xor(ri, off, 64);
            if (ov < v || (ov == v && oi < ri)) { v = ov; ri = oi; }
        }
        last = ri;
        if (lane == t) myidx = last;
    }

    int rank = 0;
    for (int j = 0; j < KK; ++j) {
        int oj = __shfl(myidx, j, 64);
        rank += (oj < myidx) || (oj == myidx && j < lane);
    }
    s_sorted[rank] = myidx;
}

// ---------------- 2a. fused selection (square G) + gather ----------------
__global__ __launch_bounds__(256) void kfused_sq(const float* __restrict__ G,
                                                 const float* __restrict__ video,
                                                 const float* __restrict__ audio,
                                                 float* __restrict__ out_v,
                                                 float* __restrict__ out_a) {
    const int b = blockIdx.x, tid = threadIdx.x;
    __shared__ int s_sorted[KK];

    if (tid < 64)
        select_wave_sq(G + (size_t)b * GBATCH, tid, s_sorted);
    __syncthreads();

    const float4* vb4 = (const float4*)(video + (size_t)b * NN * DV);
    float4* ov4 = (float4*)(out_v + (size_t)b * KK * DV);
    #pragma unroll 4
    for (int t = tid; t < KK * DV / 4; t += 256) {
        int k = t >> 8, c = t & 255;
        ov4[t] = vb4[s_sorted[k] * (DV / 4) + c];
    }
    const float4* ab4 = (const float4*)(audio + (size_t)b * NN * DA);
    float4* oa4 = (float4*)(out_a + (size_t)b * KK * DA);
    for (int t = tid; t < KK * DA / 4; t += 256) {
        int k = t >> 5, c = t & 31;
        oa4[t] = ab4[s_sorted[k] * (DA / 4) + c];
    }
}

// ---------------- 2b. fused selection (tri G) + gather ----------------
__global__ __launch_bounds__(256) void kfused_tri(const float* __restrict__ G,
                                                  const float* __restrict__ video,
                                                  const float* __restrict__ audio,
                                                  float* __restrict__ out_v,
                                                  float* __restrict__ out_a) {
    const int b = blockIdx.x, tid = threadIdx.x;
    __shared__ int s_sorted[KK];

    if (tid < 64)
        select_wave_tri(G + (size_t)b * TRI, tid, s_sorted);
    __syncthreads();

    const float4* vb4 = (const float4*)(video + (size_t)b * NN * DV);
    float4* ov4 = (float4*)(out_v + (size_t)b * KK * DV);
    #pragma unroll 4
    for (int t = tid; t < KK * DV / 4; t += 256) {
        int k = t >> 8, c = t & 255;
        ov4[t] = vb4[s_sorted[k] * (DV / 4) + c];
    }
    const float4* ab4 = (const float4*)(audio + (size_t)b * NN * DA);
    float4* oa4 = (float4*)(out_a + (size_t)b * KK * DA);
    for (int t = tid; t < KK * DA / 4; t += 256) {
        int k = t >> 5, c = t & 31;
        oa4[t] = ab4[s_sorted[k] * (DA / 4) + c];
    }
}

// ---------------- 2c. split fallback (G in out_v region) ----------------
__global__ __launch_bounds__(64) void kselect(const float* __restrict__ G,
                                              float* __restrict__ out_a) {
    __shared__ int s_sorted[KK];
    select_wave_tri(G + (size_t)blockIdx.x * TRI, threadIdx.x, s_sorted);
    __syncthreads();
    ((int*)(out_a + (size_t)blockIdx.x * KK * DA))[threadIdx.x] = s_sorted[threadIdx.x];
}

__global__ __launch_bounds__(256) void kgather(const float* __restrict__ video,
                                               const float* __restrict__ audio,
                                               float* __restrict__ out_v,
                                               float* __restrict__ out_a) {
    int b = blockIdx.x, tid = threadIdx.x;
    __shared__ int s_idx[KK];
    const int* idxp = (const int*)(out_a + (size_t)b * KK * DA);
    if (tid < KK) s_idx[tid] = idxp[tid];
    __syncthreads();

    const float4* vb4 = (const float4*)(video + (size_t)b * NN * DV);
    float4* ov4 = (float4*)(out_v + (size_t)b * KK * DV);
    #pragma unroll 4
    for (int t = tid; t < KK * DV / 4; t += 256) {
        int k = t >> 8, c = t & 255;
        ov4[t] = vb4[s_idx[k] * (DV / 4) + c];
    }
    const float4* ab4 = (const float4*)(audio + (size_t)b * NN * DA);
    float4* oa4 = (float4*)(out_a + (size_t)b * KK * DA);
    for (int t = tid; t < KK * DA / 4; t += 256) {
        int k = t >> 5, c = t & 31;
        oa4[t] = ab4[s_idx[k] * (DA / 4) + c];
    }
}

extern "C" void kernel_launch(void* const* d_in, const int* in_sizes, int n_in,
                              void* d_out, int out_size, void* d_ws, size_t ws_size,
                              hipStream_t stream) {
    const float* video = (const float*)d_in[0];
    const float* audio = (const float*)d_in[1];
    float* out   = (float*)d_out;
    float* out_v = out;
    float* out_a = out + (size_t)BB * KK * DV;

    const size_t tri_bytes = (size_t)BB * TRI * sizeof(float);   // 23.1 MB

    if (ws_size >= SQ_NEED) {
        float* G = (float*)d_ws;
        kgram3   <<<NT2 * BB, 512, 0, stream>>>(video, G);
        kfused_sq<<<BB, 256, 0, stream>>>(G, video, audio, out_v, out_a);
    } else if (ws_size >= tri_bytes) {
        float* G = (float*)d_ws;
        kgram_lds <<<NTILES * BB, 256, 0, stream>>>(video, G);
        kfused_tri<<<BB, 256, 0, stream>>>(G, video, audio, out_v, out_a);
    } else {
        float* G = out;
        kgram_lds<<<NTILES * BB, 256, 0, stream>>>(video, G);
        kselect  <<<BB, 64, 0, stream>>>(G, out_a);
        kgather  <<<BB, 256, 0, stream>>>(video, audio, out_v, out_a);
    }
}